// Round 8
// baseline (57.509 us; speedup 1.0000x reference)
//
#include <hip/hip_runtime.h>
#include <cstdint>
#include <cmath>

typedef unsigned long long ull;

// ---------------- tunables ----------------
#define SLICES 16
#define SUBCAP 384              // 64 lanes x 6 regs per wave in k4
#define NR 6
#define KT4 1024                // k4 threads (16 waves)
#define K1T 512                 // k1 threads (8 waves)
#define K1E 16                  // elements per k1 thread (4 x float4)
#define THRC 1.9f
#define NB8 8192                // k4 hist bins
#define NCK 128                 // chunks of 64 bins

// order-preserving float<->uint bijection
static __device__ __forceinline__ uint32_t f2u(float f) {
    uint32_t b = __float_as_uint(f);
    return (b & 0x80000000u) ? ~b : (b | 0x80000000u);
}
static __device__ __forceinline__ float u2f(uint32_t u) {
    uint32_t b = (u & 0x80000000u) ? (u ^ 0x80000000u) : ~u;
    return __uint_as_float(b);
}

static __device__ __forceinline__ uint32_t wave_incl_u(uint32_t v) {
    int lane = threadIdx.x & 63;
#pragma unroll
    for (int o = 1; o < 64; o <<= 1) {
        uint32_t t = __shfl_up(v, (unsigned)o);
        if (lane >= o) v += t;
    }
    return v;
}
static __device__ __forceinline__ float wave_incl_f(float v) {
    int lane = threadIdx.x & 63;
#pragma unroll
    for (int o = 1; o < 64; o <<= 1) {
        float t = __shfl_up(v, (unsigned)o);
        if (lane >= o) v += t;
    }
    return v;
}

// ---------------- two-stage descents over 8192-bin LDS hist (128 chunks) ----------------

static __device__ void ts8k_count(const uint32_t* __restrict__ h, uint32_t target,
                                  uint32_t* cs, int* out_bin, uint32_t* out_above) {
    const int tid = threadIdx.x, lane = tid & 63, wv = tid >> 6;
#pragma unroll
    for (int m = 0; m < NCK / 16; m++) {
        int cc = wv * (NCK / 16) + m;
        uint32_t x = h[cc * 64 + lane];
#pragma unroll
        for (int o = 32; o > 0; o >>= 1) x += __shfl_xor(x, o);
        if (lane == 0) cs[cc] = x;
    }
    __syncthreads();
    if (tid < 64) {
        uint32_t S = 0; int foundc = -1; uint32_t Sc = 0;
        for (int r0 = NCK - 1; r0 >= 0; r0 -= 64) {
            int cc = r0 - lane;
            uint32_t wq = (cc >= 0) ? cs[cc] : 0u;
            uint32_t incl = wave_incl_u(wq);
            uint32_t Sb = S + incl - wq;
            bool cross = (Sb < target) && (Sb + wq >= target);
            ull m = __ballot(cross);
            if (m) { int l = (int)__ffsll(m) - 1; foundc = __shfl(cc, l); Sc = __shfl(Sb, l); break; }
            S += __shfl(incl, 63);
        }
        if (foundc < 0) {
            if (lane == 0) { *out_bin = -1; *out_above = S; }
        } else {
            uint32_t wb = h[foundc * 64 + 63 - lane];
            uint32_t incb = wave_incl_u(wb);
            uint32_t Sbb = Sc + incb - wb;
            bool cr = (Sbb < target) && (Sbb + wb >= target);
            ull m2 = __ballot(cr);                 // exact integers: nonzero
            int l2 = (int)__ffsll(m2) - 1;
            if (lane == l2) { *out_bin = foundc * 64 + 63 - lane; *out_above = Sbb; }
        }
    }
    __syncthreads();
}

static __device__ void ts8k_wcross(const float* __restrict__ h, float Sbase, float target,
                                   float* cs, int* out_bin, float* out_S) {
    const int tid = threadIdx.x, lane = tid & 63, wv = tid >> 6;
#pragma unroll
    for (int m = 0; m < NCK / 16; m++) {
        int cc = wv * (NCK / 16) + m;
        float x = h[cc * 64 + lane];
#pragma unroll
        for (int o = 32; o > 0; o >>= 1) x += __shfl_xor(x, o);
        if (lane == 0) cs[cc] = x;
    }
    __syncthreads();
    if (tid < 64) {
        float S = Sbase; int foundc = -1; float Sc = 0.f;
        for (int r0 = NCK - 1; r0 >= 0; r0 -= 64) {
            int cc = r0 - lane;
            float wq = (cc >= 0) ? cs[cc] : 0.f;
            float incl = wave_incl_f(wq);
            float Sb = S + incl - wq;
            bool cross = (Sb < target) && (Sb + wq >= target);
            ull m = __ballot(cross);
            if (m) { int l = (int)__ffsll(m) - 1; foundc = __shfl(cc, l); Sc = __shfl(Sb, l); break; }
            S += __shfl(incl, 63);
        }
        if (foundc < 0) {
            if (lane == 0) { *out_bin = -1; *out_S = S; }
        } else {
            float wb = h[foundc * 64 + 63 - lane];
            float incb = wave_incl_f(wb);
            float Sbb = Sc + incb - wb;
            bool cr = (Sbb < target) && (Sbb + wb >= target);
            ull m2 = __ballot(cr);
            if (m2 == 0) cr = (lane == 63);        // deterministic forced resolution
            m2 = __ballot(cr);
            int l2 = (int)__ffsll(m2) - 1;
            if (lane == l2) { *out_bin = foundc * 64 + 63 - lane; *out_S = Sbb; }
        }
    }
    __syncthreads();
}

// ---------- 16-wave block reductions ----------
static __device__ __forceinline__ ull shflxor_u64(ull v, int o) {
    uint32_t lo = (uint32_t)v, hi = (uint32_t)(v >> 32);
    lo = __shfl_xor(lo, o); hi = __shfl_xor(hi, o);
    return ((ull)hi << 32) | (ull)lo;
}
static __device__ uint2 blk16_max2(uint32_t a, uint32_t b, uint32_t* rb /*32*/) {
#pragma unroll
    for (int o = 32; o > 0; o >>= 1) {
        uint32_t x = __shfl_xor(a, o); if (x > a) a = x;
        uint32_t y = __shfl_xor(b, o); if (y > b) b = y;
    }
    const int wv = threadIdx.x >> 6;
    if ((threadIdx.x & 63) == 0) { rb[wv] = a; rb[16 + wv] = b; }
    __syncthreads();
    if (threadIdx.x < 64) {
        const int lane = threadIdx.x;
        uint32_t ra = (lane < 16) ? rb[lane] : 0u;
        uint32_t rbv = (lane < 16) ? rb[16 + lane] : 0u;
#pragma unroll
        for (int o = 8; o > 0; o >>= 1) {
            uint32_t x = __shfl_xor(ra, o); if (x > ra) ra = x;
            uint32_t y = __shfl_xor(rbv, o); if (y > rbv) rbv = y;
        }
        if (lane == 0) { rb[0] = ra; rb[16] = rbv; }
    }
    __syncthreads();
    uint2 res; res.x = rb[0]; res.y = rb[16];
    __syncthreads();
    return res;
}
static __device__ ull blk16_max_u64(ull v, ull* rb) {
#pragma unroll
    for (int o = 32; o > 0; o >>= 1) { ull x = shflxor_u64(v, o); if (x > v) v = x; }
    const int wv = threadIdx.x >> 6;
    if ((threadIdx.x & 63) == 0) rb[wv] = v;
    __syncthreads();
    ull r = (threadIdx.x < 16) ? rb[threadIdx.x] : 0ull;
    if (threadIdx.x < 64) {
#pragma unroll
        for (int o = 8; o > 0; o >>= 1) { ull x = shflxor_u64(r, o); if (x > r) r = x; }
        if (threadIdx.x == 0) rb[0] = r;
    }
    __syncthreads();
    r = rb[0];
    __syncthreads();
    return r;
}

// ---------------- K1: fully register-resident single-chunk collect ----------------
// 512 threads x 16 elements = 8192 = sliceLen. One scan, 3 barriers total.

__global__ __launch_bounds__(K1T) void k1_collect(
    const float* __restrict__ logits, const float* __restrict__ temps,
    const float* __restrict__ noise,
    uint32_t* __restrict__ cand_u, int* __restrict__ cand_ix, float* __restrict__ cand_nz,
    uint32_t* __restrict__ candCnt, int V, int sliceLen)
{
    const int row = blockIdx.y, slice = blockIdx.x, tid = threadIdx.x;
    const int lane = tid & 63, wv = tid >> 6;   // 8 waves
    __shared__ float redm[8], reds[8], redq[8];
    __shared__ int wsum[8];

    const int base = slice * sliceLen;
    int len = V - base;
    if (len > sliceLen) len = sliceLen;
    if (len <= 0) { if (tid == 0) candCnt[row * SLICES + slice] = 0u; return; }

    const float* lg = logits + (size_t)row * (size_t)V;
    const float4* p4 = (const float4*)(lg + base);
    const int n4 = len >> 2;                    // len % 4 == 0 guaranteed by launcher

    // load 16 elements (4 float4) into registers — all loads issued up front
    float4 v[4];
    bool have[4];
#pragma unroll
    for (int q = 0; q < 4; q++) {
        const int i4 = tid * 4 + q;
        have[q] = (i4 < n4);
        v[q] = make_float4(0.f, 0.f, 0.f, 0.f);
        if (have[q]) v[q] = p4[i4];
    }

    // full-slice stats from registers
    float mx = -INFINITY, sm = 0.f, sq = 0.f;
#pragma unroll
    for (int q = 0; q < 4; q++) {
        if (have[q]) {
            mx = fmaxf(mx, fmaxf(fmaxf(v[q].x, v[q].y), fmaxf(v[q].z, v[q].w)));
            sm += (v[q].x + v[q].y) + (v[q].z + v[q].w);
            sq += (v[q].x * v[q].x + v[q].y * v[q].y) + (v[q].z * v[q].z + v[q].w * v[q].w);
        }
    }
#pragma unroll
    for (int o = 32; o > 0; o >>= 1) {
        mx = fmaxf(mx, __shfl_xor(mx, o));
        sm += __shfl_xor(sm, o);
        sq += __shfl_xor(sq, o);
    }
    if (lane == 0) { redm[wv] = mx; reds[wv] = sm; redq[wv] = sq; }
    __syncthreads();
    float m = redm[0], s = reds[0], q2 = redq[0];
    for (int w = 1; w < 8; w++) { m = fmaxf(m, redm[w]); s += reds[w]; q2 += redq[w]; }
    const float inv = 1.f / (float)len;
    const float mu = s * inv;
    const float var = fmaxf(q2 * inv - mu * mu, 0.f);
    float thr = mu + THRC * sqrtf(var);
    if (thr > m) thr = m;                       // guarantee >=1 kept (the slice max)

    // per-thread kept count + single block scan
    bool kb[16];
    int cnt = 0;
#pragma unroll
    for (int q = 0; q < 4; q++) {
        const float* e = &v[q].x;
#pragma unroll
        for (int j = 0; j < 4; j++) {
            bool kk = have[q] && (e[j] >= thr);
            kb[q * 4 + j] = kk;
            cnt += (int)kk;
        }
    }
    int inc = cnt;
#pragma unroll
    for (int o = 1; o < 64; o <<= 1) {
        int x = __shfl_up(inc, (unsigned)o);
        if (lane >= o) inc += x;
    }
    if (lane == 63) wsum[wv] = inc;
    __syncthreads();
    int woff = 0, tot = 0;
    for (int w = 0; w < 8; w++) { if (w < wv) woff += wsum[w]; tot += wsum[w]; }

    // direct write-out (order-preserving) + noise gather
    const float t = temps[row];
    const size_t gb = ((size_t)row * SLICES + slice) * SUBCAP;
    const float* nzrow = noise + (size_t)row * (size_t)V;
    int p = woff + inc - cnt;
#pragma unroll
    for (int q = 0; q < 4; q++) {
        const float* e = &v[q].x;
#pragma unroll
        for (int j = 0; j < 4; j++) {
            if (kb[q * 4 + j]) {
                if (p < SUBCAP) {
                    const int gi = base + tid * K1E + q * 4 + j;
                    cand_u[gb + p] = f2u(e[j] / t);
                    cand_ix[gb + p] = gi;
                    cand_nz[gb + p] = nzrow[gi];
                }
                p++;
            }
        }
    }
    if (tid == 0) {
        int c = tot; if (c > SUBCAP) c = SUBCAP;
        candCnt[row * SLICES + slice] = (uint32_t)c;
    }
}

// ---------------- K4: register-resident per-row finalize (proven round-7 path) ----------------

__global__ __launch_bounds__(KT4, 1) void k4_final(
    const int* __restrict__ topks, const float* __restrict__ topps,
    const float* __restrict__ minps, const uint32_t* __restrict__ candCnt,
    const uint32_t* __restrict__ cand_u, const int* __restrict__ cand_ix,
    const float* __restrict__ cand_nz, int* __restrict__ out, int V)
{
    const int row = blockIdx.x, tid = threadIdx.x;
    const int lane = tid & 63, wv = tid >> 6;
    __shared__ uint32_t s_h[NB8];            // 32 KB; aliased float for weighted
    __shared__ uint32_t s_cs[NCK];           // chunk sums (aliased float)
    __shared__ uint32_t rb2[32];
    __shared__ ull rbq[16];
    __shared__ int sh_bin; __shared__ uint32_t sh_above;
    __shared__ float sh_S; __shared__ float sh_T;
    float* fh = (float*)s_h;
    float* csf = (float*)s_cs;

    const float pp = topps[row];
    const float mp = minps[row];
    int k = topks[row]; if (k < 1) k = 1; if (k > V) k = V;

    // wave wv owns slice wv: 384 slots = lane + 64*j
    int c = (int)candCnt[row * SLICES + wv]; if (c > SUBCAP) c = SUBCAP;
    const size_t gb = ((size_t)row * SLICES + wv) * SUBCAP;

    uint32_t u[NR]; float w[NR]; float nzv[NR]; int ix[NR];
#pragma unroll
    for (int j = 0; j < NR; j++) {
        const int idx = lane + 64 * j;
        u[j] = 0u; nzv[j] = 1.f; ix[j] = 0;
        if (idx < c) {
            u[j] = cand_u[gb + idx];
            ix[j] = cand_ix[gb + idx];
            nzv[j] = cand_nz[gb + idx];
        }
    }
    uint32_t um = 0u, unm = 0u;   // max u, max ~u over live (u=0 is dead sentinel)
#pragma unroll
    for (int j = 0; j < NR; j++) {
        w[j] = (u[j] != 0u) ? expf(u2f(u[j])) : 0.f;
        if (u[j] > um) um = u[j];
        uint32_t nu = (u[j] != 0u) ? ~u[j] : 0u;
        if (nu > unm) unm = nu;
    }
    uint2 mm = blk16_max2(um, unm, rb2);
    const uint32_t umax = mm.x;
    const uint32_t ubase = ~mm.y;
    const uint32_t R = umax - ubase;
    const int sh0 = (R < (uint32_t)NB8) ? 0 : ((31 - __clz(R)) - 12);

    uint32_t r[NR];
#pragma unroll
    for (int j = 0; j < NR; j++) r[j] = u[j] - ubase;   // dead: r > R always

    // ---- exact top-k rel-threshold ukr: 13-bit-step count descent ----
    uint32_t tk = (uint32_t)k, sel = 0u;
    int sh = sh0, shPrev = sh0 + 13;
    bool first = true;
    for (;;) {
        for (int i = tid; i < NB8; i += KT4) s_h[i] = 0u;
        __syncthreads();
#pragma unroll
        for (int j = 0; j < NR; j++) {
            uint32_t rj = r[j];
            if (rj <= R && (first || (rj >> shPrev) == sel))
                atomicAdd(&s_h[(rj >> sh) & (NB8 - 1)], 1u);
        }
        __syncthreads();
        ts8k_count(s_h, tk, s_cs, &sh_bin, &sh_above);
        int b = sh_bin; uint32_t ab = sh_above;
        if (b < 0) { b = 0; ab = 0u; }           // k > n guard
        tk = (tk > ab) ? (tk - ab) : 1u;
        const int step = first ? 13 : (shPrev - sh);
        sel = (sel << step) | (uint32_t)b;
        if (sh == 0) break;
        shPrev = sh;
        sh = (sh >= 13) ? sh - 13 : 0;
        first = false;
    }
    const uint32_t ukr = sel;

    // ---- top-p: weighted descent -> rel crossing value vcr (mask = kept r < vcr) ----
    uint32_t vcr = 0u;
    {
        for (int i = tid; i < NB8; i += KT4) fh[i] = 0.f;
        __syncthreads();
#pragma unroll
        for (int j = 0; j < NR; j++) {
            uint32_t rj = r[j];
            if (rj <= R && rj >= ukr)
                atomicAdd(&fh[(rj >> sh0) & (NB8 - 1)], w[j]);
        }
        __syncthreads();
        // chunk sums + W + level-0 decision (wave 0)
#pragma unroll
        for (int m = 0; m < NCK / 16; m++) {
            int cc = wv * (NCK / 16) + m;
            float x = fh[cc * 64 + lane];
#pragma unroll
            for (int o = 32; o > 0; o >>= 1) x += __shfl_xor(x, o);
            if (lane == 0) csf[cc] = x;
        }
        __syncthreads();
        if (tid < 64) {
            float t0 = csf[lane] + csf[64 + lane];
#pragma unroll
            for (int o = 32; o > 0; o >>= 1) t0 += __shfl_xor(t0, o);
            const float Wt = t0;
            const float target = pp * Wt;
            if (lane == 0) sh_T = target;
            if (!(target > 0.f)) {
                if (lane == 0) sh_bin = -2;        // p == 0
            } else {
                float S = 0.f; int foundc = -1; float Sc = 0.f;
                for (int r0 = NCK - 1; r0 >= 0; r0 -= 64) {
                    int cc = r0 - lane;
                    float wq = (cc >= 0) ? csf[cc] : 0.f;
                    float incl = wave_incl_f(wq);
                    float Sb = S + incl - wq;
                    bool cross = (Sb < target) && (Sb + wq >= target);
                    ull m = __ballot(cross);
                    if (m) { int l = (int)__ffsll(m) - 1; foundc = __shfl(cc, l); Sc = __shfl(Sb, l); break; }
                    S += __shfl(incl, 63);
                }
                if (foundc < 0) {
                    if (lane == 0) sh_bin = -1;    // suffix never reaches target
                } else {
                    float wb = fh[foundc * 64 + 63 - lane];
                    float incb = wave_incl_f(wb);
                    float Sbb = Sc + incb - wb;
                    bool cr = (Sbb < target) && (Sbb + wb >= target);
                    ull m2 = __ballot(cr);
                    if (m2 == 0) cr = (lane == 63);
                    m2 = __ballot(cr);
                    int l2 = (int)__ffsll(m2) - 1;
                    if (lane == l2) { sh_bin = foundc * 64 + 63 - lane; sh_S = Sbb; }
                }
            }
        }
        __syncthreads();
        const int b0 = sh_bin;
        const float pW = sh_T;
        if (b0 == -2) {
            vcr = R;                               // keep only max
        } else if (b0 == -1) {
            vcr = 0u;                              // mask nothing
        } else if (sh0 == 0) {
            vcr = (uint32_t)b0;                    // exact value
        } else {
            uint32_t selp = (uint32_t)b0;
            int shPv = sh0;
            int shp = (sh0 >= 13) ? sh0 - 13 : 0;
            float Sb = sh_S;
            for (;;) {
                for (int i = tid; i < NB8; i += KT4) fh[i] = 0.f;
                __syncthreads();
#pragma unroll
                for (int j = 0; j < NR; j++) {
                    uint32_t rj = r[j];
                    if (rj <= R && rj >= ukr && (rj >> shPv) == selp)
                        atomicAdd(&fh[(rj >> shp) & (NB8 - 1)], w[j]);
                }
                __syncthreads();
                ts8k_wcross(fh, Sb, pW, csf, &sh_bin, &sh_S);
                int b = sh_bin;
                if (b < 0) { vcr = selp << shPv; break; }     // float-edge: keep whole class
                selp = (selp << (shPv - shp)) | (uint32_t)b;
                if (shp == 0) { vcr = selp; break; }
                Sb = sh_S;
                shPv = shp;
                shp = (shp >= 13) ? shp - 13 : 0;
            }
        }
        if (vcr > R) vcr = R;                      // never mask the max
    }

    // ---- min-p (Z cancels) + scale-free noise argmax over registers ----
    const float maxw = expf(u2f(umax));
    const bool use_mp = (mp > 0.f);
    const float A = mp * maxw;

    ull best = 0ull;
#pragma unroll
    for (int j = 0; j < NR; j++) {
        uint32_t rj = r[j];
        if (rj <= R && rj >= ukr && rj >= vcr) {
            float wj = w[j];
            if (!(use_mp && wj < A)) {
                float sc = wj / fmaxf(nzv[j], 1e-10f);
                ull pk = ((ull)__float_as_uint(sc) << 32) | (ull)(~(uint32_t)ix[j]);
                if (pk > best) best = pk;
            }
        }
    }
    best = blk16_max_u64(best, rbq);
    if (tid == 0) out[row] = (int)(~(uint32_t)(best & 0xffffffffull));
}

// ---------------- fallback: monolithic single-kernel path (ws too small / odd V) ----------------

#define FNT 1024
#define FNB1 16384
#define FL1SH 18
#define FCAP 8192

static __device__ void wave_desc_count_f(const uint32_t* h, int hi, int lo, uint32_t target,
                                         int* out_bin, uint32_t* out_above) {
    if (threadIdx.x < 64) {
        int lane = threadIdx.x;
        uint32_t S = 0;
        for (int r0 = hi; r0 >= lo; r0 -= 64) {
            int b = r0 - lane;
            uint32_t w = (b >= lo) ? h[b] : 0u;
            uint32_t incl = wave_incl_u(w);
            uint32_t Sb = S + incl - w;
            bool cross = (Sb < target) && (Sb + w >= target);
            ull m = __ballot(cross);
            if (m) {
                int l = (int)__ffsll(m) - 1;
                if (lane == l) { *out_bin = b; *out_above = Sb; }
                return;
            }
            S += __shfl(incl, 63);
        }
        if (lane == 0) { *out_bin = -1; *out_above = S; }
    }
}
static __device__ void wave_desc_wcross_f(const float* h, int hi, int lo, float base, float target,
                                          int* out_bin, float* out_S) {
    if (threadIdx.x < 64) {
        int lane = threadIdx.x;
        float S = base;
        for (int r0 = hi; r0 >= lo; r0 -= 64) {
            int b = r0 - lane;
            float w = (b >= lo) ? h[b] : 0.f;
            float incl = wave_incl_f(w);
            float Sb = S + (incl - w);
            bool cross = (Sb < target) && (Sb + w >= target);
            ull m = __ballot(cross);
            if (m) {
                int l = (int)__ffsll(m) - 1;
                if (lane == l) { *out_bin = b; *out_S = Sb; }
                return;
            }
            S += __shfl(incl, 63);
        }
        if (lane == 0) { *out_bin = -1; *out_S = S; }
    }
}
static __device__ void wave_desc_wvalue_f(const float* h, int hi, int lo, float base, float target,
                                          int* out_bin, float* out_S) {
    if (threadIdx.x < 64) {
        int lane = threadIdx.x;
        float S = base;
        for (int r0 = hi; r0 >= lo; r0 -= 64) {
            int b = r0 - lane;
            float w = (b >= lo) ? h[b] : 0.f;
            float incl = wave_incl_f(w);
            float Sb = S + (incl - w);
            bool cross = (w > 0.f) && (Sb >= target);
            ull m = __ballot(cross);
            if (m) {
                int l = (int)__ffsll(m) - 1;
                if (lane == l) { *out_bin = b; *out_S = Sb; }
                return;
            }
            S += __shfl(incl, 63);
        }
        if (lane == 0) { *out_bin = -1; *out_S = S; }
    }
}
static __device__ float fblk_max_f(float v, float* buf) {
    int tid = threadIdx.x;
    buf[tid] = v; __syncthreads();
    for (int o = FNT / 2; o > 0; o >>= 1) {
        if (tid < o) buf[tid] = fmaxf(buf[tid], buf[tid + o]);
        __syncthreads();
    }
    float r = buf[0]; __syncthreads();
    return r;
}
static __device__ float fblk_sum_f(float v, float* buf) {
    int tid = threadIdx.x;
    buf[tid] = v; __syncthreads();
    for (int o = FNT / 2; o > 0; o >>= 1) {
        if (tid < o) buf[tid] += buf[tid + o];
        __syncthreads();
    }
    float r = buf[0]; __syncthreads();
    return r;
}

__global__ __launch_bounds__(FNT, 1) void sampler_fallback_kernel(
    const float* __restrict__ logits, const float* __restrict__ temps,
    const int* __restrict__ topks, const float* __restrict__ topps,
    const float* __restrict__ minps, const float* __restrict__ noise,
    int* __restrict__ out, int V)
{
    __shared__ uint32_t s_hist[FNB1];
    __shared__ uint32_t s_cand[FCAP];
    __shared__ float    s_red[FNT];
    __shared__ uint32_t s_h2[512];
    __shared__ int      sh_bin;
    __shared__ uint32_t sh_above;
    __shared__ int      sh_nc;
    __shared__ int      sh_binw;
    __shared__ float    sh_S;

    const int row = blockIdx.x;
    const int tid = threadIdx.x;
    const int lane = tid & 63;
    const float t  = temps[row];
    const float pp = topps[row];
    const float mp = minps[row];
    int k = topks[row];
    if (k < 1) k = 1;
    if (k > V) k = V;
    const float* lg = logits + (size_t)row * (size_t)V;
    const float* nz = noise  + (size_t)row * (size_t)V;

    for (int i = tid; i < FNB1; i += FNT) s_hist[i] = 0u;
    __syncthreads();

    float lmax = -INFINITY;
    for (int i = tid; i < V; i += FNT) {
        float x = lg[i] / t;
        lmax = fmaxf(lmax, x);
        atomicAdd(&s_hist[f2u(x) >> FL1SH], 1u);
    }
    const float M = fblk_max_f(lmax, s_red);
    const uint32_t umax = f2u(M);
    const int bmax = (int)(umax >> FL1SH);

    wave_desc_count_f(s_hist, bmax, 0, (uint32_t)k, &sh_bin, &sh_above);
    __syncthreads();
    const int b1 = sh_bin;
    const uint32_t cntHi = sh_above;

    float* wh = reinterpret_cast<float*>(s_hist);
    for (int i = tid; i < FNB1; i += FNT) wh[i] = 0.f;
    if (tid == 0) sh_nc = 0;
    __syncthreads();
    for (int i = tid; i < V; i += FNT) {
        float x = lg[i] / t;
        uint32_t u = f2u(x);
        atomicAdd(&wh[u >> FL1SH], expf(x - M));
        bool want = ((int)(u >> FL1SH) == b1);
        ull mb = __ballot(want);
        if (want) {
            int leader = (int)__ffsll(mb) - 1;
            int off = (int)__popcll(mb & ((1ull << lane) - 1ull));
            int bse = 0;
            if (lane == leader) bse = atomicAdd(&sh_nc, (int)__popcll(mb));
            bse = __shfl(bse, leader);
            int p = bse + off;
            if (p < FCAP) s_cand[p] = u;
        }
    }
    __syncthreads();
    int nc = sh_nc; if (nc > FCAP) nc = FCAP;
    const uint32_t kk2 = (uint32_t)k - cntHi;

    for (int i = tid; i < 512; i += FNT) s_h2[i] = 0u;
    __syncthreads();
    for (int i = tid; i < nc; i += FNT) atomicAdd(&s_h2[(s_cand[i] >> 9) & 511u], 1u);
    __syncthreads();
    wave_desc_count_f(s_h2, 511, 0, kk2, &sh_bin, &sh_above);
    __syncthreads();
    const int c2 = sh_bin;
    const uint32_t kk3 = kk2 - sh_above;

    for (int i = tid; i < 512; i += FNT) s_h2[i] = 0u;
    __syncthreads();
    for (int i = tid; i < nc; i += FNT) {
        uint32_t u = s_cand[i];
        if ((int)((u >> 9) & 511u) == c2) atomicAdd(&s_h2[u & 511u], 1u);
    }
    __syncthreads();
    wave_desc_count_f(s_h2, 511, 0, kk3, &sh_bin, &sh_above);
    __syncthreads();
    const uint32_t uk = ((uint32_t)b1 << FL1SH) | ((uint32_t)c2 << 9) | (uint32_t)sh_bin;

    float wl = 0.f;
    for (int i = tid; i < nc; i += FNT) {
        uint32_t u = s_cand[i];
        if (u >= uk) wl += expf(u2f(u) - M);
    }
    const float Wb1 = fblk_sum_f(wl, s_red);
    if (tid == 0) wh[b1] = Wb1;
    __syncthreads();
    float sl = 0.f;
    for (int i = tid; i < FNB1; i += FNT)
        if (i >= b1 && i <= bmax) sl += wh[i];
    const float W = fblk_sum_f(sl, s_red);
    const float pW = pp * W;

    uint32_t up = 0u;
    float Z2 = W;
    if (pW <= 0.f) {
        up = umax - 1u;
        Z2 = 1.0f;
    } else {
        wave_desc_wcross_f(wh, bmax, b1, 0.f, pW, &sh_binw, &sh_S);
        __syncthreads();
        const int cs = sh_binw;
        if (cs >= 0) {
            const float S1 = sh_S;
            if (cs != b1) {
                if (tid == 0) sh_nc = 0;
                __syncthreads();
                for (int i = tid; i < V; i += FNT) {
                    float x = lg[i] / t;
                    uint32_t u = f2u(x);
                    bool want = (u >= uk) && ((int)(u >> FL1SH) == cs);
                    ull mb = __ballot(want);
                    if (want) {
                        int leader = (int)__ffsll(mb) - 1;
                        int off = (int)__popcll(mb & ((1ull << lane) - 1ull));
                        int bse = 0;
                        if (lane == leader) bse = atomicAdd(&sh_nc, (int)__popcll(mb));
                        bse = __shfl(bse, leader);
                        int p = bse + off;
                        if (p < FCAP) s_cand[p] = u;
                    }
                }
                __syncthreads();
                nc = sh_nc; if (nc > FCAP) nc = FCAP;
            }
            float* wh2 = reinterpret_cast<float*>(s_h2);
            for (int i = tid; i < 512; i += FNT) wh2[i] = 0.f;
            __syncthreads();
            for (int i = tid; i < nc; i += FNT) {
                uint32_t u = s_cand[i];
                if (u >= uk) atomicAdd(&wh2[(u >> 9) & 511u], expf(u2f(u) - M));
            }
            __syncthreads();
            wave_desc_wcross_f(wh2, 511, 0, S1, pW, &sh_binw, &sh_S);
            __syncthreads();
            const int c2p = sh_binw;
            if (c2p < 0) {
                uint32_t basev = (uint32_t)cs << FL1SH;
                up = basev ? basev - 1u : 0u;
                Z2 = sh_S;
            } else {
                const float S2 = sh_S;
                for (int i = tid; i < 512; i += FNT) wh2[i] = 0.f;
                __syncthreads();
                for (int i = tid; i < nc; i += FNT) {
                    uint32_t u = s_cand[i];
                    if (u >= uk && (int)((u >> 9) & 511u) == c2p)
                        atomicAdd(&wh2[u & 511u], expf(u2f(u) - M));
                }
                __syncthreads();
                wave_desc_wvalue_f(wh2, 511, 0, S2, pW, &sh_binw, &sh_S);
                __syncthreads();
                if (sh_binw < 0) {
                    uint32_t basev = ((uint32_t)cs << FL1SH) | ((uint32_t)c2p << 9);
                    up = basev ? basev - 1u : 0u;
                    Z2 = sh_S;
                } else {
                    up = ((uint32_t)cs << FL1SH) | ((uint32_t)c2p << 9) | (uint32_t)sh_binw;
                    Z2 = sh_S;
                }
            }
        }
        if (up >= umax) { up = umax - 1u; Z2 = 1.0f; }
    }
    __syncthreads();

    const bool use_mp = (mp > 0.f);
    const float thr = mp * (1.0f / Z2);

    float zl = 0.f;
    for (int i = tid; i < V; i += FNT) {
        float x = lg[i] / t;
        uint32_t u = f2u(x);
        if (u >= uk && u > up) {
            float w = expf(x - M);
            if (use_mp && (w / Z2) < thr) continue;
            zl += w;
        }
    }
    const float Z3 = fblk_sum_f(zl, s_red);

    float bs = -1.f; int bi = 0x7fffffff;
    for (int i = tid; i < V; i += FNT) {
        float x = lg[i] / t;
        uint32_t u = f2u(x);
        if (u >= uk && u > up) {
            float w = expf(x - M);
            if (use_mp && (w / Z2) < thr) continue;
            float sc = (w / Z3) / fmaxf(nz[i], 1e-10f);
            if (sc > bs) { bs = sc; bi = i; }
        }
    }
    s_red[tid] = bs;
    int* ibuf = reinterpret_cast<int*>(s_cand);
    ibuf[tid] = bi;
    __syncthreads();
    for (int o = FNT / 2; o > 0; o >>= 1) {
        if (tid < o) {
            float v2 = s_red[tid + o]; int i2 = ibuf[tid + o];
            if (v2 > s_red[tid] || (v2 == s_red[tid] && i2 < ibuf[tid])) {
                s_red[tid] = v2; ibuf[tid] = i2;
            }
        }
        __syncthreads();
    }
    if (tid == 0) out[row] = ibuf[0];
}

// ---------------- launch ----------------

extern "C" void kernel_launch(void* const* d_in, const int* in_sizes, int n_in,
                              void* d_out, int out_size, void* d_ws, size_t ws_size,
                              hipStream_t stream) {
    const float* logits = (const float*)d_in[0];
    const float* temps  = (const float*)d_in[1];
    const int*   topks  = (const int*)d_in[2];
    const float* topps  = (const float*)d_in[3];
    const float* minps  = (const float*)d_in[4];
    const float* noise  = (const float*)d_in[5];
    const int B = in_sizes[1];
    const int V = in_sizes[0] / B;
    int* out = (int*)d_out;

    const int sliceLen = (((V + SLICES - 1) / SLICES) + 1023) & ~1023;

    const size_t nslot  = (size_t)B * SLICES * SUBCAP;
    const size_t offCU  = 0;
    const size_t offCI  = offCU + nslot * 4;
    const size_t offNZ  = offCI + nslot * 4;
    const size_t offCnt = offNZ + nslot * 4;
    const size_t need   = offCnt + (size_t)B * SLICES * 4;

    if (ws_size >= need && (V & 3) == 0 &&
        (size_t)SLICES * (size_t)sliceLen >= (size_t)V &&
        sliceLen <= K1T * K1E) {
        char* ws = (char*)d_ws;
        uint32_t* cand_u  = (uint32_t*)(ws + offCU);
        int*      cand_ix = (int*)(ws + offCI);
        float*    cand_nz = (float*)(ws + offNZ);
        uint32_t* candCnt = (uint32_t*)(ws + offCnt);

        dim3 gslice(SLICES, B);
        k1_collect<<<gslice, K1T, 0, stream>>>(logits, temps, noise, cand_u, cand_ix,
                                               cand_nz, candCnt, V, sliceLen);
        k4_final<<<B, KT4, 0, stream>>>(topks, topps, minps, candCnt, cand_u, cand_ix,
                                        cand_nz, out, V);
    } else {
        sampler_fallback_kernel<<<B, FNT, 0, stream>>>(logits, temps, topks, topps, minps, noise, out, V);
    }
}

// Round 9
// 49.060 us; speedup vs baseline: 1.1722x; 1.1722x over previous
//
#include <hip/hip_runtime.h>
#include <cstdint>
#include <cmath>

typedef unsigned long long ull;

// ---------------- tunables ----------------
#define SLICES 16
#define SUBCAP 384              // 64 lanes x 6 regs per wave in k4
#define NR 6
#define KT4 1024                // k4 threads (16 waves)
#define K1T 512                 // k1 threads (8 waves)
#define K1E 16                  // elements per k1 thread (4 x float4)
#define THRC 1.9f
#define NB8 8192                // k4 hist bins
#define NCK 128                 // chunks of 64 bins

// order-preserving float<->uint bijection
static __device__ __forceinline__ uint32_t f2u(float f) {
    uint32_t b = __float_as_uint(f);
    return (b & 0x80000000u) ? ~b : (b | 0x80000000u);
}
static __device__ __forceinline__ float u2f(uint32_t u) {
    uint32_t b = (u & 0x80000000u) ? (u ^ 0x80000000u) : ~u;
    return __uint_as_float(b);
}

static __device__ __forceinline__ uint32_t wave_incl_u(uint32_t v) {
    int lane = threadIdx.x & 63;
#pragma unroll
    for (int o = 1; o < 64; o <<= 1) {
        uint32_t t = __shfl_up(v, (unsigned)o);
        if (lane >= o) v += t;
    }
    return v;
}
static __device__ __forceinline__ float wave_incl_f(float v) {
    int lane = threadIdx.x & 63;
#pragma unroll
    for (int o = 1; o < 64; o <<= 1) {
        float t = __shfl_up(v, (unsigned)o);
        if (lane >= o) v += t;
    }
    return v;
}

// ---------------- two-stage descents over 8192-bin LDS hist (128 chunks) ----------------

static __device__ void ts8k_count(const uint32_t* __restrict__ h, uint32_t target,
                                  uint32_t* cs, int* out_bin, uint32_t* out_above) {
    const int tid = threadIdx.x, lane = tid & 63, wv = tid >> 6;
#pragma unroll
    for (int m = 0; m < NCK / 16; m++) {
        int cc = wv * (NCK / 16) + m;
        uint32_t x = h[cc * 64 + lane];
#pragma unroll
        for (int o = 32; o > 0; o >>= 1) x += __shfl_xor(x, o);
        if (lane == 0) cs[cc] = x;
    }
    __syncthreads();
    if (tid < 64) {
        uint32_t S = 0; int foundc = -1; uint32_t Sc = 0;
        for (int r0 = NCK - 1; r0 >= 0; r0 -= 64) {
            int cc = r0 - lane;
            uint32_t wq = (cc >= 0) ? cs[cc] : 0u;
            uint32_t incl = wave_incl_u(wq);
            uint32_t Sb = S + incl - wq;
            bool cross = (Sb < target) && (Sb + wq >= target);
            ull m = __ballot(cross);
            if (m) { int l = (int)__ffsll(m) - 1; foundc = __shfl(cc, l); Sc = __shfl(Sb, l); break; }
            S += __shfl(incl, 63);
        }
        if (foundc < 0) {
            if (lane == 0) { *out_bin = -1; *out_above = S; }
        } else {
            uint32_t wb = h[foundc * 64 + 63 - lane];
            uint32_t incb = wave_incl_u(wb);
            uint32_t Sbb = Sc + incb - wb;
            bool cr = (Sbb < target) && (Sbb + wb >= target);
            ull m2 = __ballot(cr);                 // exact integers: nonzero
            int l2 = (int)__ffsll(m2) - 1;
            if (lane == l2) { *out_bin = foundc * 64 + 63 - lane; *out_above = Sbb; }
        }
    }
    __syncthreads();
}

static __device__ void ts8k_wcross(const float* __restrict__ h, float Sbase, float target,
                                   float* cs, int* out_bin, float* out_S) {
    const int tid = threadIdx.x, lane = tid & 63, wv = tid >> 6;
#pragma unroll
    for (int m = 0; m < NCK / 16; m++) {
        int cc = wv * (NCK / 16) + m;
        float x = h[cc * 64 + lane];
#pragma unroll
        for (int o = 32; o > 0; o >>= 1) x += __shfl_xor(x, o);
        if (lane == 0) cs[cc] = x;
    }
    __syncthreads();
    if (tid < 64) {
        float S = Sbase; int foundc = -1; float Sc = 0.f;
        for (int r0 = NCK - 1; r0 >= 0; r0 -= 64) {
            int cc = r0 - lane;
            float wq = (cc >= 0) ? cs[cc] : 0.f;
            float incl = wave_incl_f(wq);
            float Sb = S + incl - wq;
            bool cross = (Sb < target) && (Sb + wq >= target);
            ull m = __ballot(cross);
            if (m) { int l = (int)__ffsll(m) - 1; foundc = __shfl(cc, l); Sc = __shfl(Sb, l); break; }
            S += __shfl(incl, 63);
        }
        if (foundc < 0) {
            if (lane == 0) { *out_bin = -1; *out_S = S; }
        } else {
            float wb = h[foundc * 64 + 63 - lane];
            float incb = wave_incl_f(wb);
            float Sbb = Sc + incb - wb;
            bool cr = (Sbb < target) && (Sbb + wb >= target);
            ull m2 = __ballot(cr);
            if (m2 == 0) cr = (lane == 63);        // deterministic forced resolution
            m2 = __ballot(cr);
            int l2 = (int)__ffsll(m2) - 1;
            if (lane == l2) { *out_bin = foundc * 64 + 63 - lane; *out_S = Sbb; }
        }
    }
    __syncthreads();
}

// ---------- 16-wave block reductions ----------
static __device__ __forceinline__ ull shflxor_u64(ull v, int o) {
    uint32_t lo = (uint32_t)v, hi = (uint32_t)(v >> 32);
    lo = __shfl_xor(lo, o); hi = __shfl_xor(hi, o);
    return ((ull)hi << 32) | (ull)lo;
}
static __device__ uint2 blk16_max2(uint32_t a, uint32_t b, uint32_t* rb /*32*/) {
#pragma unroll
    for (int o = 32; o > 0; o >>= 1) {
        uint32_t x = __shfl_xor(a, o); if (x > a) a = x;
        uint32_t y = __shfl_xor(b, o); if (y > b) b = y;
    }
    const int wv = threadIdx.x >> 6;
    if ((threadIdx.x & 63) == 0) { rb[wv] = a; rb[16 + wv] = b; }
    __syncthreads();
    if (threadIdx.x < 64) {
        const int lane = threadIdx.x;
        uint32_t ra = (lane < 16) ? rb[lane] : 0u;
        uint32_t rbv = (lane < 16) ? rb[16 + lane] : 0u;
#pragma unroll
        for (int o = 8; o > 0; o >>= 1) {
            uint32_t x = __shfl_xor(ra, o); if (x > ra) ra = x;
            uint32_t y = __shfl_xor(rbv, o); if (y > rbv) rbv = y;
        }
        if (lane == 0) { rb[0] = ra; rb[16] = rbv; }
    }
    __syncthreads();
    uint2 res; res.x = rb[0]; res.y = rb[16];
    __syncthreads();
    return res;
}
static __device__ ull blk16_max_u64(ull v, ull* rb) {
#pragma unroll
    for (int o = 32; o > 0; o >>= 1) { ull x = shflxor_u64(v, o); if (x > v) v = x; }
    const int wv = threadIdx.x >> 6;
    if ((threadIdx.x & 63) == 0) rb[wv] = v;
    __syncthreads();
    ull r = (threadIdx.x < 16) ? rb[threadIdx.x] : 0ull;
    if (threadIdx.x < 64) {
#pragma unroll
        for (int o = 8; o > 0; o >>= 1) { ull x = shflxor_u64(r, o); if (x > r) r = x; }
        if (threadIdx.x == 0) rb[0] = r;
    }
    __syncthreads();
    r = rb[0];
    __syncthreads();
    return r;
}

// ---------------- K1: register-resident single-pass collect (coalesced, NO noise) ----------------

__global__ __launch_bounds__(K1T) void k1_collect(
    const float* __restrict__ logits, const float* __restrict__ temps,
    uint32_t* __restrict__ cand_u, int* __restrict__ cand_ix,
    uint32_t* __restrict__ candCnt, int V, int sliceLen)
{
    const int row = blockIdx.y, slice = blockIdx.x, tid = threadIdx.x;
    const int lane = tid & 63, wv = tid >> 6;   // 8 waves
    __shared__ float redm[8], reds[8], redq[8];
    __shared__ int wsum[8];

    const int base = slice * sliceLen;
    int len = V - base;
    if (len > sliceLen) len = sliceLen;
    if (len <= 0) { if (tid == 0) candCnt[row * SLICES + slice] = 0u; return; }

    const float* lg = logits + (size_t)row * (size_t)V;
    const float4* p4 = (const float4*)(lg + base);
    const int n4 = len >> 2;                    // len % 4 == 0 guaranteed by launcher

    // coalesced: float4 index = q*K1T + tid (lane-consecutive) — all loads up front
    float4 v[4];
    bool have[4];
#pragma unroll
    for (int q = 0; q < 4; q++) {
        const int i4 = q * K1T + tid;
        have[q] = (i4 < n4);
        v[q] = make_float4(0.f, 0.f, 0.f, 0.f);
        if (have[q]) v[q] = p4[i4];
    }

    // full-slice stats from registers
    float mx = -INFINITY, sm = 0.f, sq = 0.f;
#pragma unroll
    for (int q = 0; q < 4; q++) {
        if (have[q]) {
            mx = fmaxf(mx, fmaxf(fmaxf(v[q].x, v[q].y), fmaxf(v[q].z, v[q].w)));
            sm += (v[q].x + v[q].y) + (v[q].z + v[q].w);
            sq += (v[q].x * v[q].x + v[q].y * v[q].y) + (v[q].z * v[q].z + v[q].w * v[q].w);
        }
    }
#pragma unroll
    for (int o = 32; o > 0; o >>= 1) {
        mx = fmaxf(mx, __shfl_xor(mx, o));
        sm += __shfl_xor(sm, o);
        sq += __shfl_xor(sq, o);
    }
    if (lane == 0) { redm[wv] = mx; reds[wv] = sm; redq[wv] = sq; }
    __syncthreads();
    float m = redm[0], s = reds[0], q2 = redq[0];
    for (int w = 1; w < 8; w++) { m = fmaxf(m, redm[w]); s += reds[w]; q2 += redq[w]; }
    const float inv = 1.f / (float)len;
    const float mu = s * inv;
    const float var = fmaxf(q2 * inv - mu * mu, 0.f);
    float thr = mu + THRC * sqrtf(var);
    if (thr > m) thr = m;                       // guarantee >=1 kept (the slice max)

    // per-thread kept count + single block scan
    bool kb[16];
    int cnt = 0;
#pragma unroll
    for (int q = 0; q < 4; q++) {
        const float* e = &v[q].x;
#pragma unroll
        for (int j = 0; j < 4; j++) {
            bool kk = have[q] && (e[j] >= thr);
            kb[q * 4 + j] = kk;
            cnt += (int)kk;
        }
    }
    int inc = cnt;
#pragma unroll
    for (int o = 1; o < 64; o <<= 1) {
        int x = __shfl_up(inc, (unsigned)o);
        if (lane >= o) inc += x;
    }
    if (lane == 63) wsum[wv] = inc;
    __syncthreads();
    int woff = 0, tot = 0;
    for (int w = 0; w < 8; w++) { if (w < wv) woff += wsum[w]; tot += wsum[w]; }

    // direct write-out (deterministic positions; order irrelevant downstream)
    const float t = temps[row];
    const size_t gb = ((size_t)row * SLICES + slice) * SUBCAP;
    int p = woff + inc - cnt;
#pragma unroll
    for (int q = 0; q < 4; q++) {
        const float* e = &v[q].x;
#pragma unroll
        for (int j = 0; j < 4; j++) {
            if (kb[q * 4 + j]) {
                if (p < SUBCAP) {
                    const int gi = base + (q * K1T + tid) * 4 + j;
                    cand_u[gb + p] = f2u(e[j] / t);
                    cand_ix[gb + p] = gi;
                }
                p++;
            }
        }
    }
    if (tid == 0) {
        int c = tot; if (c > SUBCAP) c = SUBCAP;
        candCnt[row * SLICES + slice] = (uint32_t)c;
    }
}

// ---------------- K4: register-resident finalize; survivor-only noise gather ----------------

__global__ __launch_bounds__(KT4, 1) void k4_final(
    const int* __restrict__ topks, const float* __restrict__ topps,
    const float* __restrict__ minps, const float* __restrict__ noise,
    const uint32_t* __restrict__ candCnt, const uint32_t* __restrict__ cand_u,
    const int* __restrict__ cand_ix, int* __restrict__ out, int V)
{
    const int row = blockIdx.x, tid = threadIdx.x;
    const int lane = tid & 63, wv = tid >> 6;
    __shared__ uint32_t s_h[NB8];            // 32 KB; aliased float for weighted
    __shared__ uint32_t s_cs[NCK];           // chunk sums (aliased float)
    __shared__ uint32_t rb2[32];
    __shared__ ull rbq[16];
    __shared__ int sh_bin; __shared__ uint32_t sh_above;
    __shared__ float sh_S; __shared__ float sh_T;
    float* fh = (float*)s_h;
    float* csf = (float*)s_cs;

    const float pp = topps[row];
    const float mp = minps[row];
    int k = topks[row]; if (k < 1) k = 1; if (k > V) k = V;

    // wave wv owns slice wv: 384 slots = lane + 64*j
    int c = (int)candCnt[row * SLICES + wv]; if (c > SUBCAP) c = SUBCAP;
    const size_t gb = ((size_t)row * SLICES + wv) * SUBCAP;

    uint32_t u[NR]; float w[NR]; int ix[NR];
#pragma unroll
    for (int j = 0; j < NR; j++) {
        const int idx = lane + 64 * j;
        u[j] = 0u; ix[j] = 0;
        if (idx < c) {
            u[j] = cand_u[gb + idx];
            ix[j] = cand_ix[gb + idx];
        }
    }
    uint32_t um = 0u, unm = 0u;   // max u, max ~u over live (u=0 is dead sentinel)
#pragma unroll
    for (int j = 0; j < NR; j++) {
        w[j] = (u[j] != 0u) ? expf(u2f(u[j])) : 0.f;
        if (u[j] > um) um = u[j];
        uint32_t nu = (u[j] != 0u) ? ~u[j] : 0u;
        if (nu > unm) unm = nu;
    }
    uint2 mm = blk16_max2(um, unm, rb2);
    const uint32_t umax = mm.x;
    const uint32_t ubase = ~mm.y;
    const uint32_t R = umax - ubase;
    const int sh0 = (R < (uint32_t)NB8) ? 0 : ((31 - __clz(R)) - 12);

    uint32_t r[NR];
#pragma unroll
    for (int j = 0; j < NR; j++) r[j] = u[j] - ubase;   // dead: r > R always

    // ---- exact top-k rel-threshold ukr: 13-bit-step count descent ----
    uint32_t tk = (uint32_t)k, sel = 0u;
    int sh = sh0, shPrev = sh0 + 13;
    bool first = true;
    for (;;) {
        for (int i = tid; i < NB8; i += KT4) s_h[i] = 0u;
        __syncthreads();
#pragma unroll
        for (int j = 0; j < NR; j++) {
            uint32_t rj = r[j];
            if (rj <= R && (first || (rj >> shPrev) == sel))
                atomicAdd(&s_h[(rj >> sh) & (NB8 - 1)], 1u);
        }
        __syncthreads();
        ts8k_count(s_h, tk, s_cs, &sh_bin, &sh_above);
        int b = sh_bin; uint32_t ab = sh_above;
        if (b < 0) { b = 0; ab = 0u; }           // k > n guard
        tk = (tk > ab) ? (tk - ab) : 1u;
        const int step = first ? 13 : (shPrev - sh);
        sel = (sel << step) | (uint32_t)b;
        if (sh == 0) break;
        shPrev = sh;
        sh = (sh >= 13) ? sh - 13 : 0;
        first = false;
    }
    const uint32_t ukr = sel;

    // ---- top-p: weighted descent -> rel crossing value vcr (mask = kept r < vcr) ----
    uint32_t vcr = 0u;
    {
        for (int i = tid; i < NB8; i += KT4) fh[i] = 0.f;
        __syncthreads();
#pragma unroll
        for (int j = 0; j < NR; j++) {
            uint32_t rj = r[j];
            if (rj <= R && rj >= ukr)
                atomicAdd(&fh[(rj >> sh0) & (NB8 - 1)], w[j]);
        }
        __syncthreads();
        // chunk sums + W + level-0 decision (wave 0)
#pragma unroll
        for (int m = 0; m < NCK / 16; m++) {
            int cc = wv * (NCK / 16) + m;
            float x = fh[cc * 64 + lane];
#pragma unroll
            for (int o = 32; o > 0; o >>= 1) x += __shfl_xor(x, o);
            if (lane == 0) csf[cc] = x;
        }
        __syncthreads();
        if (tid < 64) {
            float t0 = csf[lane] + csf[64 + lane];
#pragma unroll
            for (int o = 32; o > 0; o >>= 1) t0 += __shfl_xor(t0, o);
            const float Wt = t0;
            const float target = pp * Wt;
            if (lane == 0) sh_T = target;
            if (!(target > 0.f)) {
                if (lane == 0) sh_bin = -2;        // p == 0
            } else {
                float S = 0.f; int foundc = -1; float Sc = 0.f;
                for (int r0 = NCK - 1; r0 >= 0; r0 -= 64) {
                    int cc = r0 - lane;
                    float wq = (cc >= 0) ? csf[cc] : 0.f;
                    float incl = wave_incl_f(wq);
                    float Sb = S + incl - wq;
                    bool cross = (Sb < target) && (Sb + wq >= target);
                    ull m = __ballot(cross);
                    if (m) { int l = (int)__ffsll(m) - 1; foundc = __shfl(cc, l); Sc = __shfl(Sb, l); break; }
                    S += __shfl(incl, 63);
                }
                if (foundc < 0) {
                    if (lane == 0) sh_bin = -1;    // suffix never reaches target
                } else {
                    float wb = fh[foundc * 64 + 63 - lane];
                    float incb = wave_incl_f(wb);
                    float Sbb = Sc + incb - wb;
                    bool cr = (Sbb < target) && (Sbb + wb >= target);
                    ull m2 = __ballot(cr);
                    if (m2 == 0) cr = (lane == 63);
                    m2 = __ballot(cr);
                    int l2 = (int)__ffsll(m2) - 1;
                    if (lane == l2) { sh_bin = foundc * 64 + 63 - lane; sh_S = Sbb; }
                }
            }
        }
        __syncthreads();
        const int b0 = sh_bin;
        const float pW = sh_T;
        if (b0 == -2) {
            vcr = R;                               // keep only max
        } else if (b0 == -1) {
            vcr = 0u;                              // mask nothing
        } else if (sh0 == 0) {
            vcr = (uint32_t)b0;                    // exact value
        } else {
            uint32_t selp = (uint32_t)b0;
            int shPv = sh0;
            int shp = (sh0 >= 13) ? sh0 - 13 : 0;
            float Sb = sh_S;
            for (;;) {
                for (int i = tid; i < NB8; i += KT4) fh[i] = 0.f;
                __syncthreads();
#pragma unroll
                for (int j = 0; j < NR; j++) {
                    uint32_t rj = r[j];
                    if (rj <= R && rj >= ukr && (rj >> shPv) == selp)
                        atomicAdd(&fh[(rj >> shp) & (NB8 - 1)], w[j]);
                }
                __syncthreads();
                ts8k_wcross(fh, Sb, pW, csf, &sh_bin, &sh_S);
                int b = sh_bin;
                if (b < 0) { vcr = selp << shPv; break; }     // float-edge: keep whole class
                selp = (selp << (shPv - shp)) | (uint32_t)b;
                if (shp == 0) { vcr = selp; break; }
                Sb = sh_S;
                shPv = shp;
                shp = (shp >= 13) ? shp - 13 : 0;
            }
        }
        if (vcr > R) vcr = R;                      // never mask the max
    }

    // ---- min-p (Z cancels) + survivor-only noise gather + scale-free argmax ----
    const float maxw = expf(u2f(umax));
    const bool use_mp = (mp > 0.f);
    const float A = mp * maxw;
    const float* nzrow = noise + (size_t)row * (size_t)V;

    bool live[NR];
    float nzv[NR];
#pragma unroll
    for (int j = 0; j < NR; j++) {
        uint32_t rj = r[j];
        live[j] = (rj <= R) && (rj >= ukr) && (rj >= vcr) && !(use_mp && w[j] < A);
        nzv[j] = 1.0f;
        if (live[j]) nzv[j] = nzrow[ix[j]];        // gather only survivors
    }

    ull best = 0ull;
#pragma unroll
    for (int j = 0; j < NR; j++) {
        if (live[j]) {
            float sc = w[j] / fmaxf(nzv[j], 1e-10f);
            ull pk = ((ull)__float_as_uint(sc) << 32) | (ull)(~(uint32_t)ix[j]);
            if (pk > best) best = pk;
        }
    }
    best = blk16_max_u64(best, rbq);
    if (tid == 0) out[row] = (int)(~(uint32_t)(best & 0xffffffffull));
}

// ---------------- fallback: monolithic single-kernel path (ws too small / odd V) ----------------

#define FNT 1024
#define FNB1 16384
#define FL1SH 18
#define FCAP 8192

static __device__ void wave_desc_count_f(const uint32_t* h, int hi, int lo, uint32_t target,
                                         int* out_bin, uint32_t* out_above) {
    if (threadIdx.x < 64) {
        int lane = threadIdx.x;
        uint32_t S = 0;
        for (int r0 = hi; r0 >= lo; r0 -= 64) {
            int b = r0 - lane;
            uint32_t w = (b >= lo) ? h[b] : 0u;
            uint32_t incl = wave_incl_u(w);
            uint32_t Sb = S + incl - w;
            bool cross = (Sb < target) && (Sb + w >= target);
            ull m = __ballot(cross);
            if (m) {
                int l = (int)__ffsll(m) - 1;
                if (lane == l) { *out_bin = b; *out_above = Sb; }
                return;
            }
            S += __shfl(incl, 63);
        }
        if (lane == 0) { *out_bin = -1; *out_above = S; }
    }
}
static __device__ void wave_desc_wcross_f(const float* h, int hi, int lo, float base, float target,
                                          int* out_bin, float* out_S) {
    if (threadIdx.x < 64) {
        int lane = threadIdx.x;
        float S = base;
        for (int r0 = hi; r0 >= lo; r0 -= 64) {
            int b = r0 - lane;
            float w = (b >= lo) ? h[b] : 0.f;
            float incl = wave_incl_f(w);
            float Sb = S + (incl - w);
            bool cross = (Sb < target) && (Sb + w >= target);
            ull m = __ballot(cross);
            if (m) {
                int l = (int)__ffsll(m) - 1;
                if (lane == l) { *out_bin = b; *out_S = Sb; }
                return;
            }
            S += __shfl(incl, 63);
        }
        if (lane == 0) { *out_bin = -1; *out_S = S; }
    }
}
static __device__ void wave_desc_wvalue_f(const float* h, int hi, int lo, float base, float target,
                                          int* out_bin, float* out_S) {
    if (threadIdx.x < 64) {
        int lane = threadIdx.x;
        float S = base;
        for (int r0 = hi; r0 >= lo; r0 -= 64) {
            int b = r0 - lane;
            float w = (b >= lo) ? h[b] : 0.f;
            float incl = wave_incl_f(w);
            float Sb = S + (incl - w);
            bool cross = (w > 0.f) && (Sb >= target);
            ull m = __ballot(cross);
            if (m) {
                int l = (int)__ffsll(m) - 1;
                if (lane == l) { *out_bin = b; *out_S = Sb; }
                return;
            }
            S += __shfl(incl, 63);
        }
        if (lane == 0) { *out_bin = -1; *out_S = S; }
    }
}
static __device__ float fblk_max_f(float v, float* buf) {
    int tid = threadIdx.x;
    buf[tid] = v; __syncthreads();
    for (int o = FNT / 2; o > 0; o >>= 1) {
        if (tid < o) buf[tid] = fmaxf(buf[tid], buf[tid + o]);
        __syncthreads();
    }
    float r = buf[0]; __syncthreads();
    return r;
}
static __device__ float fblk_sum_f(float v, float* buf) {
    int tid = threadIdx.x;
    buf[tid] = v; __syncthreads();
    for (int o = FNT / 2; o > 0; o >>= 1) {
        if (tid < o) buf[tid] += buf[tid + o];
        __syncthreads();
    }
    float r = buf[0]; __syncthreads();
    return r;
}

__global__ __launch_bounds__(FNT, 1) void sampler_fallback_kernel(
    const float* __restrict__ logits, const float* __restrict__ temps,
    const int* __restrict__ topks, const float* __restrict__ topps,
    const float* __restrict__ minps, const float* __restrict__ noise,
    int* __restrict__ out, int V)
{
    __shared__ uint32_t s_hist[FNB1];
    __shared__ uint32_t s_cand[FCAP];
    __shared__ float    s_red[FNT];
    __shared__ uint32_t s_h2[512];
    __shared__ int      sh_bin;
    __shared__ uint32_t sh_above;
    __shared__ int      sh_nc;
    __shared__ int      sh_binw;
    __shared__ float    sh_S;

    const int row = blockIdx.x;
    const int tid = threadIdx.x;
    const int lane = tid & 63;
    const float t  = temps[row];
    const float pp = topps[row];
    const float mp = minps[row];
    int k = topks[row];
    if (k < 1) k = 1;
    if (k > V) k = V;
    const float* lg = logits + (size_t)row * (size_t)V;
    const float* nz = noise  + (size_t)row * (size_t)V;

    for (int i = tid; i < FNB1; i += FNT) s_hist[i] = 0u;
    __syncthreads();

    float lmax = -INFINITY;
    for (int i = tid; i < V; i += FNT) {
        float x = lg[i] / t;
        lmax = fmaxf(lmax, x);
        atomicAdd(&s_hist[f2u(x) >> FL1SH], 1u);
    }
    const float M = fblk_max_f(lmax, s_red);
    const uint32_t umax = f2u(M);
    const int bmax = (int)(umax >> FL1SH);

    wave_desc_count_f(s_hist, bmax, 0, (uint32_t)k, &sh_bin, &sh_above);
    __syncthreads();
    const int b1 = sh_bin;
    const uint32_t cntHi = sh_above;

    float* wh = reinterpret_cast<float*>(s_hist);
    for (int i = tid; i < FNB1; i += FNT) wh[i] = 0.f;
    if (tid == 0) sh_nc = 0;
    __syncthreads();
    for (int i = tid; i < V; i += FNT) {
        float x = lg[i] / t;
        uint32_t u = f2u(x);
        atomicAdd(&wh[u >> FL1SH], expf(x - M));
        bool want = ((int)(u >> FL1SH) == b1);
        ull mb = __ballot(want);
        if (want) {
            int leader = (int)__ffsll(mb) - 1;
            int off = (int)__popcll(mb & ((1ull << lane) - 1ull));
            int bse = 0;
            if (lane == leader) bse = atomicAdd(&sh_nc, (int)__popcll(mb));
            bse = __shfl(bse, leader);
            int p = bse + off;
            if (p < FCAP) s_cand[p] = u;
        }
    }
    __syncthreads();
    int nc = sh_nc; if (nc > FCAP) nc = FCAP;
    const uint32_t kk2 = (uint32_t)k - cntHi;

    for (int i = tid; i < 512; i += FNT) s_h2[i] = 0u;
    __syncthreads();
    for (int i = tid; i < nc; i += FNT) atomicAdd(&s_h2[(s_cand[i] >> 9) & 511u], 1u);
    __syncthreads();
    wave_desc_count_f(s_h2, 511, 0, kk2, &sh_bin, &sh_above);
    __syncthreads();
    const int c2 = sh_bin;
    const uint32_t kk3 = kk2 - sh_above;

    for (int i = tid; i < 512; i += FNT) s_h2[i] = 0u;
    __syncthreads();
    for (int i = tid; i < nc; i += FNT) {
        uint32_t u = s_cand[i];
        if ((int)((u >> 9) & 511u) == c2) atomicAdd(&s_h2[u & 511u], 1u);
    }
    __syncthreads();
    wave_desc_count_f(s_h2, 511, 0, kk3, &sh_bin, &sh_above);
    __syncthreads();
    const uint32_t uk = ((uint32_t)b1 << FL1SH) | ((uint32_t)c2 << 9) | (uint32_t)sh_bin;

    float wl = 0.f;
    for (int i = tid; i < nc; i += FNT) {
        uint32_t u = s_cand[i];
        if (u >= uk) wl += expf(u2f(u) - M);
    }
    const float Wb1 = fblk_sum_f(wl, s_red);
    if (tid == 0) wh[b1] = Wb1;
    __syncthreads();
    float sl = 0.f;
    for (int i = tid; i < FNB1; i += FNT)
        if (i >= b1 && i <= bmax) sl += wh[i];
    const float W = fblk_sum_f(sl, s_red);
    const float pW = pp * W;

    uint32_t up = 0u;
    float Z2 = W;
    if (pW <= 0.f) {
        up = umax - 1u;
        Z2 = 1.0f;
    } else {
        wave_desc_wcross_f(wh, bmax, b1, 0.f, pW, &sh_binw, &sh_S);
        __syncthreads();
        const int cs = sh_binw;
        if (cs >= 0) {
            const float S1 = sh_S;
            if (cs != b1) {
                if (tid == 0) sh_nc = 0;
                __syncthreads();
                for (int i = tid; i < V; i += FNT) {
                    float x = lg[i] / t;
                    uint32_t u = f2u(x);
                    bool want = (u >= uk) && ((int)(u >> FL1SH) == cs);
                    ull mb = __ballot(want);
                    if (want) {
                        int leader = (int)__ffsll(mb) - 1;
                        int off = (int)__popcll(mb & ((1ull << lane) - 1ull));
                        int bse = 0;
                        if (lane == leader) bse = atomicAdd(&sh_nc, (int)__popcll(mb));
                        bse = __shfl(bse, leader);
                        int p = bse + off;
                        if (p < FCAP) s_cand[p] = u;
                    }
                }
                __syncthreads();
                nc = sh_nc; if (nc > FCAP) nc = FCAP;
            }
            float* wh2 = reinterpret_cast<float*>(s_h2);
            for (int i = tid; i < 512; i += FNT) wh2[i] = 0.f;
            __syncthreads();
            for (int i = tid; i < nc; i += FNT) {
                uint32_t u = s_cand[i];
                if (u >= uk) atomicAdd(&wh2[(u >> 9) & 511u], expf(u2f(u) - M));
            }
            __syncthreads();
            wave_desc_wcross_f(wh2, 511, 0, S1, pW, &sh_binw, &sh_S);
            __syncthreads();
            const int c2p = sh_binw;
            if (c2p < 0) {
                uint32_t basev = (uint32_t)cs << FL1SH;
                up = basev ? basev - 1u : 0u;
                Z2 = sh_S;
            } else {
                const float S2 = sh_S;
                for (int i = tid; i < 512; i += FNT) wh2[i] = 0.f;
                __syncthreads();
                for (int i = tid; i < nc; i += FNT) {
                    uint32_t u = s_cand[i];
                    if (u >= uk && (int)((u >> 9) & 511u) == c2p)
                        atomicAdd(&wh2[u & 511u], expf(u2f(u) - M));
                }
                __syncthreads();
                wave_desc_wvalue_f(wh2, 511, 0, S2, pW, &sh_binw, &sh_S);
                __syncthreads();
                if (sh_binw < 0) {
                    uint32_t basev = ((uint32_t)cs << FL1SH) | ((uint32_t)c2p << 9);
                    up = basev ? basev - 1u : 0u;
                    Z2 = sh_S;
                } else {
                    up = ((uint32_t)cs << FL1SH) | ((uint32_t)c2p << 9) | (uint32_t)sh_binw;
                    Z2 = sh_S;
                }
            }
        }
        if (up >= umax) { up = umax - 1u; Z2 = 1.0f; }
    }
    __syncthreads();

    const bool use_mp = (mp > 0.f);
    const float thr = mp * (1.0f / Z2);

    float zl = 0.f;
    for (int i = tid; i < V; i += FNT) {
        float x = lg[i] / t;
        uint32_t u = f2u(x);
        if (u >= uk && u > up) {
            float w = expf(x - M);
            if (use_mp && (w / Z2) < thr) continue;
            zl += w;
        }
    }
    const float Z3 = fblk_sum_f(zl, s_red);

    float bs = -1.f; int bi = 0x7fffffff;
    for (int i = tid; i < V; i += FNT) {
        float x = lg[i] / t;
        uint32_t u = f2u(x);
        if (u >= uk && u > up) {
            float w = expf(x - M);
            if (use_mp && (w / Z2) < thr) continue;
            float sc = (w / Z3) / fmaxf(nz[i], 1e-10f);
            if (sc > bs) { bs = sc; bi = i; }
        }
    }
    s_red[tid] = bs;
    int* ibuf = reinterpret_cast<int*>(s_cand);
    ibuf[tid] = bi;
    __syncthreads();
    for (int o = FNT / 2; o > 0; o >>= 1) {
        if (tid < o) {
            float v2 = s_red[tid + o]; int i2 = ibuf[tid + o];
            if (v2 > s_red[tid] || (v2 == s_red[tid] && i2 < ibuf[tid])) {
                s_red[tid] = v2; ibuf[tid] = i2;
            }
        }
        __syncthreads();
    }
    if (tid == 0) out[row] = ibuf[0];
}

// ---------------- launch ----------------

extern "C" void kernel_launch(void* const* d_in, const int* in_sizes, int n_in,
                              void* d_out, int out_size, void* d_ws, size_t ws_size,
                              hipStream_t stream) {
    const float* logits = (const float*)d_in[0];
    const float* temps  = (const float*)d_in[1];
    const int*   topks  = (const int*)d_in[2];
    const float* topps  = (const float*)d_in[3];
    const float* minps  = (const float*)d_in[4];
    const float* noise  = (const float*)d_in[5];
    const int B = in_sizes[1];
    const int V = in_sizes[0] / B;
    int* out = (int*)d_out;

    const int sliceLen = (((V + SLICES - 1) / SLICES) + 1023) & ~1023;

    const size_t nslot  = (size_t)B * SLICES * SUBCAP;
    const size_t offCU  = 0;
    const size_t offCI  = offCU + nslot * 4;
    const size_t offCnt = offCI + nslot * 4;
    const size_t need   = offCnt + (size_t)B * SLICES * 4;

    if (ws_size >= need && (V & 3) == 0 &&
        (size_t)SLICES * (size_t)sliceLen >= (size_t)V &&
        sliceLen <= K1T * K1E) {
        char* ws = (char*)d_ws;
        uint32_t* cand_u  = (uint32_t*)(ws + offCU);
        int*      cand_ix = (int*)(ws + offCI);
        uint32_t* candCnt = (uint32_t*)(ws + offCnt);

        dim3 gslice(SLICES, B);
        k1_collect<<<gslice, K1T, 0, stream>>>(logits, temps, cand_u, cand_ix,
                                               candCnt, V, sliceLen);
        k4_final<<<B, KT4, 0, stream>>>(topks, topps, minps, noise, candCnt,
                                        cand_u, cand_ix, out, V);
    } else {
        sampler_fallback_kernel<<<B, FNT, 0, stream>>>(logits, temps, topks, topps, minps, noise, out, V);
    }
}